// Round 3
// baseline (433.218 us; speedup 1.0000x reference)
//
#include <hip/hip_runtime.h>
#include <hip/hip_bf16.h>

// B=4, T=2048, C=1024, H=16, D=64
//
// ws (ushort elems), 67.1MB:
//   ws0 [0..8388608)         q [B,H,T,D] (pre-scaled by 0.125*log2e) -> WoutT
//   ws1 [8388608..16777216)  k [B,H,T,D]
//   ws2 [16777216..25165824) vT [B,H,D,T]
//   ws3 [25165824..33554432) v [B,H,T,D] -> y [B*T,C]
// d_out scratch early (dead before final GEMM): xbf [8192][1024], WqkvT [3072][1024]

using f32x4 = __attribute__((ext_vector_type(4))) float;
using s16x8 = __attribute__((ext_vector_type(8))) short;
using s16x4 = __attribute__((ext_vector_type(4))) short;

#define MFMA16(a, b, c) __builtin_amdgcn_mfma_f32_16x16x32_bf16(a, b, c, 0, 0, 0)

__device__ __forceinline__ unsigned short f2bf(float f) {
    unsigned u = __builtin_bit_cast(unsigned, f);
    u += 0x7fffu + ((u >> 16) & 1u);
    return (unsigned short)(u >> 16);
}

__device__ __forceinline__ void gl_lds16(const void* g, void* l) {
    __builtin_amdgcn_global_load_lds(
        (const __attribute__((address_space(1))) void*)g,
        (__attribute__((address_space(3))) void*)l, 16, 0, 0);
}

// ---------------------------------------------------------------------------
__global__ __launch_bounds__(256) void cvt_x(const float* __restrict__ x,
                                             unsigned short* __restrict__ xb, int n4) {
    int i = blockIdx.x * 256 + threadIdx.x;
    if (i < n4) {
        f32x4 v = ((const f32x4*)x)[i];
        s16x4 o;
        o[0] = (short)f2bf(v[0]); o[1] = (short)f2bf(v[1]);
        o[2] = (short)f2bf(v[2]); o[3] = (short)f2bf(v[3]);
        ((s16x4*)xb)[i] = o;
    }
}

// ---------------------------------------------------------------------------
__global__ __launch_bounds__(256) void cvt_tr(const float* __restrict__ W,
                                              unsigned short* __restrict__ Wt,
                                              int R, int Cc) {
    __shared__ unsigned short tile[64][72];
    const int r0 = blockIdx.x * 64, c0 = blockIdx.y * 64;
    const int tid = threadIdx.x;
    const int r = tid >> 4, c4 = (tid & 15) * 4;
#pragma unroll
    for (int i = 0; i < 4; ++i) {
        f32x4 v = *(const f32x4*)(W + (size_t)(r0 + r + i * 16) * Cc + c0 + c4);
#pragma unroll
        for (int j = 0; j < 4; ++j) tile[r + i * 16][c4 + j] = f2bf(v[j]);
    }
    __syncthreads();
#pragma unroll
    for (int i = 0; i < 4; ++i) {
        s16x4 o;
#pragma unroll
        for (int j = 0; j < 4; ++j) o[j] = (short)tile[c4 + j][r + i * 16];
        *(s16x4*)(Wt + (size_t)(c0 + r + i * 16) * R + r0 + c4) = o;
    }
}

// ---------------------------------------------------------------------------
__global__ __launch_bounds__(256) void tr_v(const unsigned short* __restrict__ v,
                                            unsigned short* __restrict__ vt) {
    __shared__ unsigned short tile[64][72];
    const int t0 = blockIdx.x * 64;
    const int bh = blockIdx.y;
    const unsigned short* src = v + (size_t)bh * 131072;
    unsigned short* dst = vt + (size_t)bh * 131072;
    const int tid = threadIdx.x;
    const int r = tid >> 3, c = (tid & 7) * 8;
#pragma unroll
    for (int i = 0; i < 2; ++i)
        *(s16x8*)(&tile[r + i * 32][c]) =
            *(const s16x8*)(src + (size_t)(t0 + r + i * 32) * 64 + c);
    __syncthreads();
#pragma unroll
    for (int i = 0; i < 2; ++i) {
        s16x8 o;
#pragma unroll
        for (int j = 0; j < 8; ++j) o[j] = (short)tile[c + j][r + i * 32];
        *(s16x8*)(dst + (size_t)(r + i * 32) * 2048 + t0 + c) = o;
    }
}

// ---------------------------------------------------------------------------
// GEMM (m97 structure). MODE 0 scatters to q/k/v (q pre-scaled); MODE 1 fp32.
// ---------------------------------------------------------------------------
template <int MODE>
__global__ __launch_bounds__(256) void gemm_bt(
    const unsigned short* __restrict__ A, const unsigned short* __restrict__ Bt,
    const float* __restrict__ bias,
    unsigned short* __restrict__ qp, unsigned short* __restrict__ kp,
    unsigned short* __restrict__ vp, float* __restrict__ outp,
    int M, int N, int K)
{
    __shared__ unsigned short As[128 * 32];
    __shared__ unsigned short Bs[128 * 32];
    const int tid  = threadIdx.x;
    const int lane = tid & 63, w = tid >> 6;
    const int wm = w >> 1, wn = w & 1;
    const int g = lane >> 4, li = lane & 15;
    const int m0 = blockIdx.x * 128, n0 = blockIdx.y * 128;
    const int srow = lane >> 2, sc = (lane & 3) * 8;

    f32x4 acc[4][4] = {};

    for (int k0 = 0; k0 < K; k0 += 32) {
        __syncthreads();
#pragma unroll
        for (int j = 0; j < 2; ++j) {
            const int rr = w * 32 + j * 16;
            gl_lds16(A  + (size_t)(m0 + rr + srow) * K + k0 + sc, As + rr * 32);
            gl_lds16(Bt + (size_t)(n0 + rr + srow) * K + k0 + sc, Bs + rr * 32);
        }
        __syncthreads();

        s16x8 af[4], bf[4];
#pragma unroll
        for (int i = 0; i < 4; ++i)
            af[i] = *(const s16x8*)(As + (wm * 64 + i * 16 + li) * 32 + g * 8);
#pragma unroll
        for (int i = 0; i < 4; ++i)
            bf[i] = *(const s16x8*)(Bs + (wn * 64 + i * 16 + li) * 32 + g * 8);
#pragma unroll
        for (int mi = 0; mi < 4; ++mi)
#pragma unroll
            for (int ni = 0; ni < 4; ++ni)
                acc[mi][ni] = MFMA16(af[mi], bf[ni], acc[mi][ni]);
    }

#pragma unroll
    for (int mi = 0; mi < 4; ++mi)
#pragma unroll
        for (int ni = 0; ni < 4; ++ni)
#pragma unroll
            for (int r = 0; r < 4; ++r) {
                const int m = m0 + wm * 64 + mi * 16 + g * 4 + r;
                const int n = n0 + wn * 64 + ni * 16 + li;
                float val = acc[mi][ni][r] + bias[n];
                if (MODE == 0) {
                    const int s = n >> 10, h = (n >> 6) & 15, d = n & 63;
                    const int b = m >> 11, tt = m & 2047;
                    if (s == 0) val *= 0.1803368801111143f;  // 0.125 * log2(e)
                    unsigned short* dst = (s == 0) ? qp : (s == 1) ? kp : vp;
                    dst[((size_t)(b * 16 + h) * 2048 + tt) * 64 + d] = f2bf(val);
                } else {
                    outp[(size_t)m * N + n] = val;
                }
            }
}

// ---------------------------------------------------------------------------
// Flash attention, causal — wave-independent (NO barriers). 4 waves/block,
// each wave owns 32 q-rows. K and vT read directly from global (L2-resident);
// only the P->A-fragment transpose goes through per-wave LDS. exp2 domain
// (q pre-scaled by 0.125*log2e in the GEMM epilogue).
// ---------------------------------------------------------------------------
__device__ __forceinline__ void softmax_blk(
    f32x4 (&sfr)[4], f32x4 (&Ov)[4], float (&m)[4], float (&l)[4],
    unsigned short (*PsRow)[72], int rowbase, int kbase, bool need_mask,
    int g, int li)
{
#pragma unroll
    for (int r = 0; r < 4; ++r) {
        const int row = rowbase + g * 4 + r;
        float mx = -1e30f;
#pragma unroll
        for (int nf = 0; nf < 4; ++nf) {
            float v = sfr[nf][r];
            if (need_mask && (kbase + nf * 16 + li > row)) v = -1e30f;
            sfr[nf][r] = v;
            mx = fmaxf(mx, v);
        }
        mx = fmaxf(mx, __shfl_xor(mx, 1));
        mx = fmaxf(mx, __shfl_xor(mx, 2));
        mx = fmaxf(mx, __shfl_xor(mx, 4));
        mx = fmaxf(mx, __shfl_xor(mx, 8));

        const float mnew = fmaxf(m[r], mx);
        const float fac  = __builtin_amdgcn_exp2f(m[r] - mnew);
        m[r] = mnew;

        float rs = 0.f;
#pragma unroll
        for (int nf = 0; nf < 4; ++nf) {
            float p = __builtin_amdgcn_exp2f(sfr[nf][r] - mnew);
            sfr[nf][r] = p;
            rs += p;
        }
        rs += __shfl_xor(rs, 1);
        rs += __shfl_xor(rs, 2);
        rs += __shfl_xor(rs, 4);
        rs += __shfl_xor(rs, 8);
        l[r] = l[r] * fac + rs;

#pragma unroll
        for (int nf = 0; nf < 4; ++nf) {
            Ov[nf][r] *= fac;
            PsRow[g * 4 + r][nf * 16 + li] = f2bf(sfr[nf][r]);
        }
    }
}

__global__ __launch_bounds__(256, 4) void attn_k(
    const unsigned short* __restrict__ qbuf,
    const unsigned short* __restrict__ kbuf,
    const unsigned short* __restrict__ vtbuf,
    unsigned short* __restrict__ ybuf)
{
    __shared__ unsigned short Ps[4][32][72];  // per-wave P staging

    const int tid  = threadIdx.x;
    const int lane = tid & 63, w = tid >> 6;
    const int g = lane >> 4, li = lane & 15;
    const int bh  = blockIdx.y;
    const int wq0 = blockIdx.x * 128 + w * 32;

    const unsigned short* qb  = qbuf  + (size_t)bh * 131072;
    const unsigned short* kb  = kbuf  + (size_t)bh * 131072;
    const unsigned short* vtb = vtbuf + (size_t)bh * 131072;

    s16x8 qf[2][2];
#pragma unroll
    for (int mi = 0; mi < 2; ++mi) {
        const unsigned short* qr = qb + (size_t)(wq0 + mi * 16 + li) * 64 + g * 8;
        qf[mi][0] = *(const s16x8*)qr;
        qf[mi][1] = *(const s16x8*)(qr + 32);
    }

    f32x4 O[2][4] = {};
    float mrow[2][4], lrow[2][4];
#pragma unroll
    for (int mi = 0; mi < 2; ++mi)
#pragma unroll
        for (int r = 0; r < 4; ++r) { mrow[mi][r] = -1e30f; lrow[mi][r] = 0.f; }

    const int nkb = ((wq0 + 31) >> 6) + 1;
    for (int kbi = 0; kbi < nkb; ++kbi) {
        const int kbase = kbi * 64;

        // S = Q K^T (both mi share the K fragments)
        f32x4 s0[4], s1[4];
#pragma unroll
        for (int nf = 0; nf < 4; ++nf) {
            const unsigned short* kr = kb + (size_t)(kbase + nf * 16 + li) * 64 + g * 8;
            s16x8 kf0 = *(const s16x8*)kr;
            s16x8 kf1 = *(const s16x8*)(kr + 32);
            f32x4 a = {}, b = {};
            a = MFMA16(qf[0][0], kf0, a); a = MFMA16(qf[0][1], kf1, a);
            b = MFMA16(qf[1][0], kf0, b); b = MFMA16(qf[1][1], kf1, b);
            s0[nf] = a; s1[nf] = b;
        }

        softmax_blk(s0, O[0], mrow[0], lrow[0], &Ps[w][0],
                    wq0, kbase, kbase + 63 > wq0, g, li);
        softmax_blk(s1, O[1], mrow[1], lrow[1], &Ps[w][16],
                    wq0 + 16, kbase, kbase + 63 > wq0 + 16, g, li);

        // P fragments (A layout: row = li, k-chunk = g)
        s16x8 pf[2][2];
#pragma unroll
        for (int mi = 0; mi < 2; ++mi) {
            pf[mi][0] = *(const s16x8*)(&Ps[w][mi * 16 + li][g * 8]);
            pf[mi][1] = *(const s16x8*)(&Ps[w][mi * 16 + li][32 + g * 8]);
        }

        // PV: vT gives contiguous 16B B-operand reads (both mi share V frags)
#pragma unroll
        for (int nf = 0; nf < 4; ++nf) {
            const unsigned short* vr = vtb + (size_t)(nf * 16 + li) * 2048 + kbase + g * 8;
            s16x8 vf0 = *(const s16x8*)vr;
            s16x8 vf1 = *(const s16x8*)(vr + 32);
            O[0][nf] = MFMA16(pf[0][0], vf0, O[0][nf]);
            O[0][nf] = MFMA16(pf[0][1], vf1, O[0][nf]);
            O[1][nf] = MFMA16(pf[1][0], vf0, O[1][nf]);
            O[1][nf] = MFMA16(pf[1][1], vf1, O[1][nf]);
        }
    }

    const int b = bh >> 4, h = bh & 15;
#pragma unroll
    for (int mi = 0; mi < 2; ++mi)
#pragma unroll
        for (int r = 0; r < 4; ++r) {
            const float rinv = __builtin_amdgcn_rcpf(lrow[mi][r]);
            const int row = wq0 + mi * 16 + g * 4 + r;
#pragma unroll
            for (int nf = 0; nf < 4; ++nf) {
                const int d = nf * 16 + li;
                ybuf[((size_t)(b * 2048 + row)) * 1024 + h * 64 + d] =
                    f2bf(O[mi][nf][r] * rinv);
            }
        }
}

extern "C" void kernel_launch(void* const* d_in, const int* in_sizes, int n_in,
                              void* d_out, int out_size, void* d_ws, size_t ws_size,
                              hipStream_t stream)
{
    const float* x    = (const float*)d_in[0];
    const float* Wqkv = (const float*)d_in[1];
    const float* bqkv = (const float*)d_in[2];
    const float* Wout = (const float*)d_in[3];
    const float* bout = (const float*)d_in[4];

    unsigned short* ws0 = (unsigned short*)d_ws;
    unsigned short* ws1 = ws0 + (size_t)8388608;
    unsigned short* ws2 = ws0 + (size_t)2 * 8388608;
    unsigned short* ws3 = ws0 + (size_t)3 * 8388608;

    unsigned short* xbf   = (unsigned short*)d_out;
    unsigned short* WqkvT = xbf + (size_t)8388608;

    cvt_x<<<8192, 256, 0, stream>>>(x, xbf, 2097152);
    cvt_tr<<<dim3(16, 48), 256, 0, stream>>>(Wqkv, WqkvT, 1024, 3072);
    gemm_bt<0><<<dim3(64, 24), 256, 0, stream>>>(
        xbf, WqkvT, bqkv, ws0, ws1, ws3, nullptr, 8192, 3072, 1024);
    tr_v<<<dim3(32, 64), 256, 0, stream>>>(ws3, ws2);
    attn_k<<<dim3(16, 64), 256, 0, stream>>>(ws0, ws1, ws2, ws3);
    cvt_tr<<<dim3(16, 16), 256, 0, stream>>>(Wout, ws0, 1024, 1024);
    gemm_bt<1><<<dim3(64, 8), 256, 0, stream>>>(
        ws3, ws0, bout, nullptr, nullptr, nullptr, (float*)d_out, 8192, 1024, 1024);
}